// Round 1
// baseline (4167.022 us; speedup 1.0000x reference)
//
#include <hip/hip_runtime.h>
#include <cfloat>
#include <math.h>

#define NUM_EMB 8192
#define DIM 256
#define NROWS 32768
#define TM 64
#define TK 64
#define PSTR 260   // 256 + 4 floats pad: keeps float4 alignment, breaks bank aliasing

// ---------------- codebook squared norms ----------------
__global__ __launch_bounds__(64) void vq_norms(const float* __restrict__ cb,
                                               float* __restrict__ cbn) {
    int k = blockIdx.x;
    int lane = threadIdx.x;
    float4 v = ((const float4*)(cb + (size_t)k * DIM))[lane];
    float s = v.x * v.x + v.y * v.y + v.z * v.z + v.w * v.w;
    #pragma unroll
    for (int o = 32; o > 0; o >>= 1) s += __shfl_down(s, o, 64);
    if (lane == 0) cbn[k] = s;
}

// ---------------- fused GEMM + argmin ----------------
// score_k = ||e_k||^2 - 2 x.e_k  (same argmin as full distance, computed at
// small scale => ~1e-9 accurate => matches an exact/f64 argmin)
__global__ __launch_bounds__(256) void vq_argmin(const float* __restrict__ x,
                                                 const float* __restrict__ cb,
                                                 const float* __restrict__ cbn,
                                                 int* __restrict__ idx) {
    __shared__ float xs[TM][PSTR];
    __shared__ float es[TK][PSTR];
    __shared__ float Bs[TK];
    __shared__ float red_s[TM][17];
    __shared__ int   red_i[TM][17];

    const int tid = threadIdx.x;
    const int m0 = blockIdx.x * TM;
    const int ty = tid >> 4, tx = tid & 15;

    // stage x tile (64 rows x 256) once; resident for whole kernel
    for (int t = tid; t < TM * (DIM / 4); t += 256) {
        int r = t >> 6, c = (t & 63) << 2;
        float4 v = *(const float4*)(x + (size_t)(m0 + r) * DIM + c);
        *(float4*)&xs[r][c] = v;
    }

    float minv[4];
    int   mini[4];
    #pragma unroll
    for (int i = 0; i < 4; i++) { minv[i] = FLT_MAX; mini[i] = 0; }

    for (int kc = 0; kc < NUM_EMB; kc += TK) {
        __syncthreads();   // previous chunk's compute done (also covers xs on iter 0)
        for (int t = tid; t < TK * (DIM / 4); t += 256) {
            int r = t >> 6, c = (t & 63) << 2;
            float4 v = *(const float4*)(cb + (size_t)(kc + r) * DIM + c);
            *(float4*)&es[r][c] = v;
        }
        if (tid < TK) Bs[tid] = cbn[kc + tid];
        __syncthreads();

        float acc[4][4];
        #pragma unroll
        for (int i = 0; i < 4; i++)
            #pragma unroll
            for (int j = 0; j < 4; j++) acc[i][j] = 0.f;

        #pragma unroll 2
        for (int d = 0; d < DIM; d += 4) {
            float4 a[4], b[4];
            #pragma unroll
            for (int i = 0; i < 4; i++) a[i] = *(const float4*)&xs[ty + 16 * i][d];
            #pragma unroll
            for (int j = 0; j < 4; j++) b[j] = *(const float4*)&es[tx + 16 * j][d];
            #pragma unroll
            for (int i = 0; i < 4; i++)
                #pragma unroll
                for (int j = 0; j < 4; j++)
                    acc[i][j] += a[i].x * b[j].x + a[i].y * b[j].y +
                                 a[i].z * b[j].z + a[i].w * b[j].w;
        }

        #pragma unroll
        for (int j = 0; j < 4; j++) {
            int c = tx + 16 * j;
            float bn = Bs[c];
            int gidx = kc + c;
            #pragma unroll
            for (int i = 0; i < 4; i++) {
                float s = bn - 2.0f * acc[i][j];
                // strict < with ascending k keeps the lowest index (np.argmin rule)
                if (s < minv[i]) { minv[i] = s; mini[i] = gidx; }
            }
        }
    }

    __syncthreads();
    #pragma unroll
    for (int i = 0; i < 4; i++) {
        red_s[ty + 16 * i][tx] = minv[i];
        red_i[ty + 16 * i][tx] = mini[i];
    }
    __syncthreads();
    if (tid < TM) {
        float best = red_s[tid][0];
        int   bi   = red_i[tid][0];
        #pragma unroll
        for (int t = 1; t < 16; t++) {
            float s = red_s[tid][t];
            int   ii = red_i[tid][t];
            if (s < best || (s == best && ii < bi)) { best = s; bi = ii; }
        }
        idx[m0 + tid] = bi;
    }
}

// ---------------- gather + straight-through output + loss + counts ----------------
__global__ __launch_bounds__(256) void vq_out(const float* __restrict__ x,
                                              const float* __restrict__ cb,
                                              const int* __restrict__ idx,
                                              float* __restrict__ out,
                                              unsigned int* __restrict__ counts,
                                              double* __restrict__ loss_sum) {
    int row  = blockIdx.x * 4 + (threadIdx.x >> 6);
    int lane = threadIdx.x & 63;
    int id = idx[row];
    float4 q  = ((const float4*)(cb + (size_t)id * DIM))[lane];
    float4 xv = ((const float4*)(x + (size_t)row * DIM))[lane];
    float dx = q.x - xv.x, dy = q.y - xv.y, dz = q.z - xv.z, dw = q.w - xv.w;
    float4 o;
    o.x = xv.x + dx; o.y = xv.y + dy; o.z = xv.z + dz; o.w = xv.w + dw;
    ((float4*)(out + (size_t)row * DIM))[lane] = o;
    float s = dx * dx + dy * dy + dz * dz + dw * dw;
    #pragma unroll
    for (int o2 = 32; o2 > 0; o2 >>= 1) s += __shfl_down(s, o2, 64);
    if (lane == 0) {
        atomicAdd(loss_sum, (double)s);
        atomicAdd(&counts[id], 1u);
    }
}

// ---------------- finalize loss + perplexity ----------------
__global__ __launch_bounds__(256) void vq_fin(const unsigned int* __restrict__ counts,
                                              const double* __restrict__ loss_sum,
                                              float* __restrict__ out_tail) {
    __shared__ double sh[256];
    int tid = threadIdx.x;
    double h = 0.0;
    for (int k = tid; k < NUM_EMB; k += 256) {
        float p = (float)counts[k] / 32768.0f;   // ref: counts.astype(f32) / N
        h += (double)p * log((double)p + 1e-10);
    }
    sh[tid] = h;
    __syncthreads();
    for (int o = 128; o > 0; o >>= 1) {
        if (tid < o) sh[tid] += sh[tid + o];
        __syncthreads();
    }
    if (tid == 0) {
        double mean = loss_sum[0] / (double)((size_t)NROWS * DIM);
        out_tail[0] = (float)(1.25 * mean);   // q_latent + 0.25*e_latent (identical fwd)
        out_tail[1] = (float)exp(-sh[0]);
    }
}

extern "C" void kernel_launch(void* const* d_in, const int* in_sizes, int n_in,
                              void* d_out, int out_size, void* d_ws, size_t ws_size,
                              hipStream_t stream) {
    const float* x  = (const float*)d_in[0];
    const float* cb = (const float*)d_in[1];
    char* ws = (char*)d_ws;
    // ws layout: [0,8) double loss_sum | [16, 16+32K) counts | then idx | then cbn
    double* loss_sum     = (double*)ws;
    unsigned int* counts = (unsigned int*)(ws + 16);
    int* idx             = (int*)(ws + 16 + 4 * NUM_EMB);
    float* cbn           = (float*)(ws + 16 + 4 * NUM_EMB + 4 * NROWS);
    float* out = (float*)d_out;

    hipMemsetAsync(ws, 0, 16 + 4 * NUM_EMB, stream);           // zero loss_sum + counts
    vq_norms <<<NUM_EMB, 64, 0, stream>>>(cb, cbn);
    vq_argmin<<<NROWS / TM, 256, 0, stream>>>(x, cb, cbn, idx);
    vq_out   <<<NROWS / 4, 256, 0, stream>>>(x, cb, idx, out, counts, loss_sum);
    vq_fin   <<<1, 256, 0, stream>>>(counts, loss_sum, out + (size_t)NROWS * DIM);
}

// Round 3
// 752.540 us; speedup vs baseline: 5.5373x; 5.5373x over previous
//
#include <hip/hip_runtime.h>
#include <cfloat>
#include <math.h>

#define NUM_EMB 8192
#define DIM 256
#define NROWS 32768

typedef short s8v __attribute__((ext_vector_type(8)));   // 8 bf16 in 4 VGPRs
typedef float f32x4 __attribute__((ext_vector_type(4)));

#define GL2LDS(g, l) __builtin_amdgcn_global_load_lds( \
    (const __attribute__((address_space(1))) void*)(g), \
    (__attribute__((address_space(3))) void*)(l), 16, 0, 0)

// fp32 -> bf16 (round-to-nearest-even), header-version-independent
__device__ __forceinline__ unsigned short f2bf(float f) {
    unsigned int u = __float_as_uint(f);
    u += 0x7fffu + ((u >> 16) & 1u);
    return (unsigned short)(u >> 16);
}

// ---------------- x fp32 -> bf16 ----------------
__global__ __launch_bounds__(256) void vq_cvt_x(const float* __restrict__ x,
                                                unsigned short* __restrict__ xb) {
    int i = blockIdx.x * 256 + threadIdx.x;          // over float4 groups
    float4 v = ((const float4*)x)[i];
    ushort4 o;
    o.x = f2bf(v.x); o.y = f2bf(v.y); o.z = f2bf(v.z); o.w = f2bf(v.w);
    ((ushort4*)xb)[i] = o;
}

// ---------------- codebook norms (fp32) + bf16 conversion ----------------
__global__ __launch_bounds__(64) void vq_norms(const float* __restrict__ cb,
                                               float* __restrict__ cbn,
                                               unsigned short* __restrict__ cbb) {
    int k = blockIdx.x;
    int lane = threadIdx.x;
    float4 v = ((const float4*)(cb + (size_t)k * DIM))[lane];
    ushort4 o;
    o.x = f2bf(v.x); o.y = f2bf(v.y); o.z = f2bf(v.z); o.w = f2bf(v.w);
    ((ushort4*)(cbb + (size_t)k * DIM))[lane] = o;
    float s = v.x * v.x + v.y * v.y + v.z * v.z + v.w * v.w;
    #pragma unroll
    for (int off = 32; off > 0; off >>= 1) s += __shfl_down(s, off, 64);
    if (lane == 0) cbn[k] = s;
}

// ---------------- MFMA GEMM + fused argmin ----------------
// score[m][n] = ||e_n||^2 - 2 * x_m . e_n ; per-block (128x128 tile) argmin
// packed as (monotone_f32_key << 32)|col -> u64 min preserves np tie-break.
__global__ __launch_bounds__(256) void vq_argmin_mfma(
        const unsigned short* __restrict__ xb,
        const unsigned short* __restrict__ cbb,
        const float* __restrict__ cbn,
        unsigned long long* __restrict__ partial) {
    __shared__ __align__(16) unsigned short As[128 * 64];  // [row][k] bf16, swizzled
    __shared__ __align__(16) unsigned short Bs[128 * 64];
    __shared__ float bns[128];
    __shared__ unsigned long long redk[2][128];

    const int tid = threadIdx.x;
    const int lane = tid & 63;
    const int w = tid >> 6;           // wave 0..3
    const int wm = w >> 1, wn = w & 1;
    const int l15 = lane & 15, q = lane >> 4;
    const int bx = blockIdx.x & 63;   // N tile (fastest -> A-tile reuse in L2)
    const int by = blockIdx.x >> 6;   // M tile
    const int m0 = by * 128, n0 = bx * 128;

    if (tid < 128) bns[tid] = cbn[n0 + tid];

    f32x4 acc[4][4];
    #pragma unroll
    for (int i = 0; i < 4; i++)
        #pragma unroll
        for (int j = 0; j < 4; j++) acc[i][j] = (f32x4)0.f;

    const int sub = lane >> 3;        // row-within-segment 0..7
    const int sl  = lane & 7;         // 16B slot 0..7

    for (int kc = 0; kc < 4; kc++) {
        __syncthreads();
        #pragma unroll
        for (int t = 0; t < 4; t++) {
            int seg = t * 4 + w;                       // wave-uniform
            int row = seg * 8 + sub;
            int blk = sl ^ (row & 7);                  // XOR swizzle (bank-conflict-free reads)
            const char* gA = (const char*)xb + (size_t)(m0 + row) * 512 + kc * 128 + blk * 16;
            const char* gB = (const char*)cbb + (size_t)(n0 + row) * 512 + kc * 128 + blk * 16;
            GL2LDS(gA, (char*)As + seg * 1024);
            GL2LDS(gB, (char*)Bs + seg * 1024);
        }
        __syncthreads();   // compiler emits vmcnt(0) drain here

        #pragma unroll
        for (int ks = 0; ks < 2; ks++) {
            s8v a[4], b[4];
            #pragma unroll
            for (int i = 0; i < 4; i++) {
                int row = wm * 64 + i * 16 + l15;
                int P = (ks * 4 + q) ^ (row & 7);
                a[i] = *(const s8v*)(As + row * 64 + P * 8);
            }
            #pragma unroll
            for (int j = 0; j < 4; j++) {
                int row = wn * 64 + j * 16 + l15;
                int P = (ks * 4 + q) ^ (row & 7);
                b[j] = *(const s8v*)(Bs + row * 64 + P * 8);
            }
            #pragma unroll
            for (int i = 0; i < 4; i++)
                #pragma unroll
                for (int j = 0; j < 4; j++)
                    acc[i][j] = __builtin_amdgcn_mfma_f32_16x16x32_bf16(
                        a[i], b[j], acc[i][j], 0, 0, 0);
        }
    }

    // epilogue: per-lane min over j, shuffle-min over the 16 col-lanes
    #pragma unroll
    for (int i = 0; i < 4; i++) {
        #pragma unroll
        for (int r = 0; r < 4; r++) {
            float bestv = FLT_MAX;
            int bestc = 0;
            #pragma unroll
            for (int j = 0; j < 4; j++) {
                int cl = wn * 64 + j * 16 + l15;
                float v = bns[cl] - 2.0f * acc[i][j][r];
                if (v < bestv) { bestv = v; bestc = cl; }   // ascending cols: keeps lowest
            }
            unsigned int bits = __float_as_uint(bestv);
            unsigned int sk = (bits & 0x80000000u) ? ~bits : (bits | 0x80000000u);
            unsigned long long key =
                ((unsigned long long)sk << 32) | (unsigned int)(n0 + bestc);
            #pragma unroll
            for (int off = 8; off >= 1; off >>= 1) {
                unsigned long long o = __shfl_xor(key, off, 16);
                if (o < key) key = o;
            }
            if (l15 == 0) redk[wn][wm * 64 + i * 16 + q * 4 + r] = key;
        }
    }
    __syncthreads();
    if (tid < 128) {
        unsigned long long k0 = redk[0][tid], k1 = redk[1][tid];
        partial[(size_t)(m0 + tid) * 64 + bx] = k0 < k1 ? k0 : k1;
    }
}

// ---------------- reduce 64 partials per row -> index ----------------
__global__ __launch_bounds__(256) void vq_reduce(
        const unsigned long long* __restrict__ partial, int* __restrict__ idx) {
    int row = blockIdx.x * 4 + (threadIdx.x >> 6);
    int lane = threadIdx.x & 63;
    unsigned long long k = partial[(size_t)row * 64 + lane];
    #pragma unroll
    for (int off = 32; off >= 1; off >>= 1) {
        unsigned long long o = __shfl_xor(k, off, 64);
        if (o < k) k = o;
    }
    if (lane == 0) idx[row] = (int)(unsigned int)(k & 0xffffffffu);
}

// ---------------- gather + straight-through output + loss + counts ----------------
__global__ __launch_bounds__(256) void vq_out(const float* __restrict__ x,
                                              const float* __restrict__ cb,
                                              const int* __restrict__ idx,
                                              float* __restrict__ out,
                                              unsigned int* __restrict__ counts,
                                              double* __restrict__ loss_sum) {
    int row  = blockIdx.x * 4 + (threadIdx.x >> 6);
    int lane = threadIdx.x & 63;
    int id = idx[row];
    float4 qv = ((const float4*)(cb + (size_t)id * DIM))[lane];
    float4 xv = ((const float4*)(x + (size_t)row * DIM))[lane];
    float dx = qv.x - xv.x, dy = qv.y - xv.y, dz = qv.z - xv.z, dw = qv.w - xv.w;
    float4 o;
    o.x = xv.x + dx; o.y = xv.y + dy; o.z = xv.z + dz; o.w = xv.w + dw;
    ((float4*)(out + (size_t)row * DIM))[lane] = o;
    float s = dx * dx + dy * dy + dz * dz + dw * dw;
    #pragma unroll
    for (int o2 = 32; o2 > 0; o2 >>= 1) s += __shfl_down(s, o2, 64);
    if (lane == 0) {
        atomicAdd(loss_sum, (double)s);
        atomicAdd(&counts[id], 1u);
    }
}

// ---------------- finalize loss + perplexity ----------------
__global__ __launch_bounds__(256) void vq_fin(const unsigned int* __restrict__ counts,
                                              const double* __restrict__ loss_sum,
                                              float* __restrict__ out_tail) {
    __shared__ double sh[256];
    int tid = threadIdx.x;
    double h = 0.0;
    for (int k = tid; k < NUM_EMB; k += 256) {
        float p = (float)counts[k] / 32768.0f;
        h += (double)p * log((double)p + 1e-10);
    }
    sh[tid] = h;
    __syncthreads();
    for (int o = 128; o > 0; o >>= 1) {
        if (tid < o) sh[tid] += sh[tid + o];
        __syncthreads();
    }
    if (tid == 0) {
        double mean = loss_sum[0] / (double)((size_t)NROWS * DIM);
        out_tail[0] = (float)(1.25 * mean);
        out_tail[1] = (float)exp(-sh[0]);
    }
}

extern "C" void kernel_launch(void* const* d_in, const int* in_sizes, int n_in,
                              void* d_out, int out_size, void* d_ws, size_t ws_size,
                              hipStream_t stream) {
    const float* x  = (const float*)d_in[0];
    const float* cb = (const float*)d_in[1];
    char* ws = (char*)d_ws;
    // ws layout (bytes):
    double* loss_sum       = (double*)ws;                        // [0,8)
    unsigned int* counts   = (unsigned int*)(ws + 256);          // 32768 B
    int* idx               = (int*)(ws + 33024);                 // 131072 B
    float* cbn             = (float*)(ws + 164096);              // 32768 B
    unsigned short* xb     = (unsigned short*)(ws + 196864);     // 16 MB bf16 x
    unsigned short* cbb    = (unsigned short*)(ws + 196864 + 16777216);   // 4 MB bf16 cb
    unsigned long long* pp = (unsigned long long*)(ws + 196864 + 16777216 + 4194304); // 16 MB
    float* out = (float*)d_out;

    (void)hipMemsetAsync(ws, 0, 33024, stream);   // zero loss_sum + counts
    vq_cvt_x      <<<8192, 256, 0, stream>>>(x, xb);
    vq_norms      <<<NUM_EMB, 64, 0, stream>>>(cb, cbn, cbb);
    vq_argmin_mfma<<<16384, 256, 0, stream>>>(xb, cbb, cbn, pp);
    vq_reduce     <<<NROWS / 4, 256, 0, stream>>>(pp, idx);
    vq_out        <<<NROWS / 4, 256, 0, stream>>>(x, cb, idx, out, counts, loss_sum);
    vq_fin        <<<1, 256, 0, stream>>>(counts, loss_sum, out + (size_t)NROWS * DIM);
}

// Round 4
// 364.427 us; speedup vs baseline: 11.4344x; 2.0650x over previous
//
#include <hip/hip_runtime.h>
#include <cfloat>
#include <math.h>

#define NUM_EMB 8192
#define DIM 256
#define NROWS 32768

typedef short s8v __attribute__((ext_vector_type(8)));   // 8 bf16 in 4 VGPRs
typedef float f32x4 __attribute__((ext_vector_type(4)));

#define GL2LDS(g, l) __builtin_amdgcn_global_load_lds( \
    (const __attribute__((address_space(1))) void*)(g), \
    (__attribute__((address_space(3))) void*)(l), 16, 0, 0)

// fp32 -> bf16 (round-to-nearest-even), header-version-independent
__device__ __forceinline__ unsigned short f2bf(float f) {
    unsigned int u = __float_as_uint(f);
    u += 0x7fffu + ((u >> 16) & 1u);
    return (unsigned short)(u >> 16);
}

// ---------------- x fp32 -> bf16 ----------------
__global__ __launch_bounds__(256) void vq_cvt_x(const float* __restrict__ x,
                                                unsigned short* __restrict__ xb) {
    int i = blockIdx.x * 256 + threadIdx.x;          // over float4 groups
    float4 v = ((const float4*)x)[i];
    ushort4 o;
    o.x = f2bf(v.x); o.y = f2bf(v.y); o.z = f2bf(v.z); o.w = f2bf(v.w);
    ((ushort4*)xb)[i] = o;
}

// ---------------- codebook norms (fp32) + bf16 conversion ----------------
__global__ __launch_bounds__(64) void vq_norms(const float* __restrict__ cb,
                                               float* __restrict__ cbn,
                                               unsigned short* __restrict__ cbb) {
    int k = blockIdx.x;
    int lane = threadIdx.x;
    float4 v = ((const float4*)(cb + (size_t)k * DIM))[lane];
    ushort4 o;
    o.x = f2bf(v.x); o.y = f2bf(v.y); o.z = f2bf(v.z); o.w = f2bf(v.w);
    ((ushort4*)(cbb + (size_t)k * DIM))[lane] = o;
    float s = v.x * v.x + v.y * v.y + v.z * v.z + v.w * v.w;
    #pragma unroll
    for (int off = 32; off > 0; off >>= 1) s += __shfl_down(s, off, 64);
    if (lane == 0) cbn[k] = s;
}

// ---------------- MFMA GEMM + fused argmin ----------------
// score[m][n] = ||e_n||^2 - 2 * x_m . e_n ; per-block (128x128 tile) argmin
// packed as (monotone_f32_key << 32)|col -> u64 min preserves np tie-break.
__global__ __launch_bounds__(256) void vq_argmin_mfma(
        const unsigned short* __restrict__ xb,
        const unsigned short* __restrict__ cbb,
        const float* __restrict__ cbn,
        unsigned long long* __restrict__ partial) {
    __shared__ __align__(16) unsigned short As[128 * 64];  // [row][k] bf16, swizzled
    __shared__ __align__(16) unsigned short Bs[128 * 64];
    __shared__ float bns[128];
    __shared__ unsigned long long redk[2][128];

    const int tid = threadIdx.x;
    const int lane = tid & 63;
    const int w = tid >> 6;           // wave 0..3
    const int wm = w >> 1, wn = w & 1;
    const int l15 = lane & 15, q = lane >> 4;
    const int bx = blockIdx.x & 63;   // N tile (fastest -> A-tile reuse in L2)
    const int by = blockIdx.x >> 6;   // M tile
    const int m0 = by * 128, n0 = bx * 128;

    if (tid < 128) bns[tid] = cbn[n0 + tid];

    f32x4 acc[4][4];
    #pragma unroll
    for (int i = 0; i < 4; i++)
        #pragma unroll
        for (int j = 0; j < 4; j++) acc[i][j] = (f32x4)0.f;

    const int sub = lane >> 3;        // row-within-segment 0..7
    const int sl  = lane & 7;         // 16B slot 0..7

    for (int kc = 0; kc < 4; kc++) {
        __syncthreads();
        #pragma unroll
        for (int t = 0; t < 4; t++) {
            int seg = t * 4 + w;                       // wave-uniform
            int row = seg * 8 + sub;
            int blk = sl ^ (row & 7);                  // XOR swizzle (bank-conflict-free reads)
            const char* gA = (const char*)xb + (size_t)(m0 + row) * 512 + kc * 128 + blk * 16;
            const char* gB = (const char*)cbb + (size_t)(n0 + row) * 512 + kc * 128 + blk * 16;
            GL2LDS(gA, (char*)As + seg * 1024);
            GL2LDS(gB, (char*)Bs + seg * 1024);
        }
        __syncthreads();   // compiler emits vmcnt(0) drain here

        #pragma unroll
        for (int ks = 0; ks < 2; ks++) {
            s8v a[4], b[4];
            #pragma unroll
            for (int i = 0; i < 4; i++) {
                int row = wm * 64 + i * 16 + l15;
                int P = (ks * 4 + q) ^ (row & 7);
                a[i] = *(const s8v*)(As + row * 64 + P * 8);
            }
            #pragma unroll
            for (int j = 0; j < 4; j++) {
                int row = wn * 64 + j * 16 + l15;
                int P = (ks * 4 + q) ^ (row & 7);
                b[j] = *(const s8v*)(Bs + row * 64 + P * 8);
            }
            #pragma unroll
            for (int i = 0; i < 4; i++)
                #pragma unroll
                for (int j = 0; j < 4; j++)
                    acc[i][j] = __builtin_amdgcn_mfma_f32_16x16x32_bf16(
                        a[i], b[j], acc[i][j], 0, 0, 0);
        }
    }

    // epilogue: per-lane min over j, shuffle-min over the 16 col-lanes
    #pragma unroll
    for (int i = 0; i < 4; i++) {
        #pragma unroll
        for (int r = 0; r < 4; r++) {
            float bestv = FLT_MAX;
            int bestc = 0;
            #pragma unroll
            for (int j = 0; j < 4; j++) {
                int cl = wn * 64 + j * 16 + l15;
                float v = bns[cl] - 2.0f * acc[i][j][r];
                if (v < bestv) { bestv = v; bestc = cl; }   // ascending cols: keeps lowest
            }
            unsigned int bits = __float_as_uint(bestv);
            unsigned int sk = (bits & 0x80000000u) ? ~bits : (bits | 0x80000000u);
            unsigned long long key =
                ((unsigned long long)sk << 32) | (unsigned int)(n0 + bestc);
            #pragma unroll
            for (int off = 8; off >= 1; off >>= 1) {
                unsigned long long o = __shfl_xor(key, off, 16);
                if (o < key) key = o;
            }
            if (l15 == 0) redk[wn][wm * 64 + i * 16 + q * 4 + r] = key;
        }
    }
    __syncthreads();
    if (tid < 128) {
        unsigned long long k0 = redk[0][tid], k1 = redk[1][tid];
        partial[(size_t)(m0 + tid) * 64 + bx] = k0 < k1 ? k0 : k1;
    }
}

// ---------------- reduce 64 partials per row -> index ----------------
__global__ __launch_bounds__(256) void vq_reduce(
        const unsigned long long* __restrict__ partial, int* __restrict__ idx) {
    int row = blockIdx.x * 4 + (threadIdx.x >> 6);
    int lane = threadIdx.x & 63;
    unsigned long long k = partial[(size_t)row * 64 + lane];
    #pragma unroll
    for (int off = 32; off >= 1; off >>= 1) {
        unsigned long long o = __shfl_xor(k, off, 64);
        if (o < k) k = o;
    }
    if (lane == 0) idx[row] = (int)(unsigned int)(k & 0xffffffffu);
}

// ---------------- gather + straight-through output + loss partials + counts ----------------
// One non-atomic loss partial per block (G12: reduce first). counts atomics are
// spread over 8192 addresses -> not a serialization point.
__global__ __launch_bounds__(256) void vq_out(const float* __restrict__ x,
                                              const float* __restrict__ cb,
                                              const int* __restrict__ idx,
                                              float* __restrict__ out,
                                              unsigned int* __restrict__ counts,
                                              double* __restrict__ loss_part) {
    __shared__ float wred[4];
    int wv   = threadIdx.x >> 6;
    int row  = blockIdx.x * 4 + wv;
    int lane = threadIdx.x & 63;
    int id = idx[row];
    float4 qv = ((const float4*)(cb + (size_t)id * DIM))[lane];
    float4 xv = ((const float4*)(x + (size_t)row * DIM))[lane];
    float dx = qv.x - xv.x, dy = qv.y - xv.y, dz = qv.z - xv.z, dw = qv.w - xv.w;
    float4 o;
    o.x = xv.x + dx; o.y = xv.y + dy; o.z = xv.z + dz; o.w = xv.w + dw;
    ((float4*)(out + (size_t)row * DIM))[lane] = o;
    float s = dx * dx + dy * dy + dz * dz + dw * dw;
    #pragma unroll
    for (int o2 = 32; o2 > 0; o2 >>= 1) s += __shfl_down(s, o2, 64);
    if (lane == 0) {
        wred[wv] = s;
        atomicAdd(&counts[id], 1u);
    }
    __syncthreads();
    if (threadIdx.x == 0) {
        loss_part[blockIdx.x] =
            (double)wred[0] + (double)wred[1] + (double)wred[2] + (double)wred[3];
    }
}

// ---------------- finalize loss + perplexity ----------------
__global__ __launch_bounds__(256) void vq_fin(const unsigned int* __restrict__ counts,
                                              const double* __restrict__ loss_part,
                                              float* __restrict__ out_tail) {
    __shared__ double sh[256];
    __shared__ double sl[256];
    int tid = threadIdx.x;
    double h = 0.0;
    for (int k = tid; k < NUM_EMB; k += 256) {
        float p = (float)counts[k] / 32768.0f;
        h += (double)p * log((double)p + 1e-10);
    }
    double ls = 0.0;
    for (int b = tid; b < NROWS / 4; b += 256) ls += loss_part[b];
    sh[tid] = h;
    sl[tid] = ls;
    __syncthreads();
    for (int o = 128; o > 0; o >>= 1) {
        if (tid < o) { sh[tid] += sh[tid + o]; sl[tid] += sl[tid + o]; }
        __syncthreads();
    }
    if (tid == 0) {
        double mean = sl[0] / (double)((size_t)NROWS * DIM);
        out_tail[0] = (float)(1.25 * mean);
        out_tail[1] = (float)exp(-sh[0]);
    }
}

extern "C" void kernel_launch(void* const* d_in, const int* in_sizes, int n_in,
                              void* d_out, int out_size, void* d_ws, size_t ws_size,
                              hipStream_t stream) {
    const float* x  = (const float*)d_in[0];
    const float* cb = (const float*)d_in[1];
    char* ws = (char*)d_ws;
    // ws layout (bytes):
    unsigned int* counts   = (unsigned int*)(ws + 256);          // 32768 B
    int* idx               = (int*)(ws + 33024);                 // 131072 B
    float* cbn             = (float*)(ws + 164096);              // 32768 B
    unsigned short* xb     = (unsigned short*)(ws + 196864);     // 16 MB bf16 x
    unsigned short* cbb    = (unsigned short*)(ws + 196864 + 16777216);   // 4 MB bf16 cb
    unsigned long long* pp = (unsigned long long*)(ws + 196864 + 16777216 + 4194304); // 16 MB
    double* loss_part      = (double*)(ws + 196864 + 16777216 + 4194304 + 16777216); // 64 KB
    float* out = (float*)d_out;

    (void)hipMemsetAsync(ws, 0, 33024, stream);   // zero counts
    vq_cvt_x      <<<8192, 256, 0, stream>>>(x, xb);
    vq_norms      <<<NUM_EMB, 64, 0, stream>>>(cb, cbn, cbb);
    vq_argmin_mfma<<<16384, 256, 0, stream>>>(xb, cbb, cbn, pp);
    vq_reduce     <<<NROWS / 4, 256, 0, stream>>>(pp, idx);
    vq_out        <<<NROWS / 4, 256, 0, stream>>>(x, cb, idx, out, counts, loss_part);
    vq_fin        <<<1, 256, 0, stream>>>(counts, loss_part, out + (size_t)NROWS * DIM);
}